// Round 15
// baseline (163.988 us; speedup 1.0000x reference)
//
#include <hip/hip_runtime.h>

// Problem constants
#define BB 8
#define CIN 256
#define NE 64
#define HH 128
#define WW 128
#define HW (HH*WW)
#define TOPK 8

#define TS   16              // 16x16 pixel tile, 512 blocks of 512 threads
#define NTH  512
#define HLX  18
#define NSP  (HLX*HLX)       // 324 spatial positions incl halo
#define NG   (NSP*4)         // 1296 (s, cp) staging groups, 8 ch each
#define CC   32              // channels per K-chunk
#define NCH  (CIN/CC)        // 8 chunks
#define XROW 48              // x LDS row bytes: 32 ch fp8 + 16 pad (16B-aligned b128, stride-12 bank spread)
#define XBUF (NSP*XROW)      // 15552 B per x buffer
// w chunk: 2 tapgroup blocks [64e][144B] (taps tg*4..+3, 32ch each + 16 pad) + tap8 block [64e][40B]
#define WTG  (64*144)        // 9216
#define W8OFF (2*WTG)        // 18432
#define WCH  (2*WTG + 64*40) // 20992 B per w chunk

// d_out layout (float32 view): weights | indices | counts | new_bias
#define W_OFF  0
#define I_OFF  (BB*TOPK*HH*WW)
#define C_OFF  (2*BB*TOPK*HH*WW)
#define NB_OFF (C_OFF + NE)

#define WIMG_BYTES (NCH*WCH)   // 167936

using f32x4 = __attribute__((ext_vector_type(4))) float;
using i32x4 = __attribute__((ext_vector_type(4))) int;
using i32x8 = __attribute__((ext_vector_type(8))) int;

// 32B LDS load as v8i32 (two aligned b128s)
#define LDB256(PTR) __builtin_shufflevector(*(const i32x4*)(PTR), \
                    *(const i32x4*)((PTR) + 16), 0, 1, 2, 3, 4, 5, 6, 7)

#define GLDS16(gsrc, ldst) __builtin_amdgcn_global_load_lds( \
    (const __attribute__((address_space(1))) void*)(gsrc),   \
    (__attribute__((address_space(3))) void*)(ldst), 16, 0, 0)

// ---- prep: w fp32 [e][cin][3][3] -> fp8 e4m3 (x64 scaled) image ----
// taps 0-7 in two 128B-packed blocks (k = (tap&3)*32 + ch, canonical order),
// tap 8 in a 40B-row block. Also zeroes gcount (replaces memset dispatch).
__global__ void prep_w(const float* __restrict__ wg, char* __restrict__ wimg,
                       int* __restrict__ gcount) {
    if (blockIdx.x == 0 && threadIdx.x < NE) gcount[threadIdx.x] = 0;
    int i = blockIdx.x * 256 + threadIdx.x;
    if (i >= NCH * 9 * NE * 8) return;
    int cq = i & 7; int t = i >> 3;          // cq: 4-channel quad
    int e  = t & 63; int t2 = t >> 6;
    int tap = t2 % 9; int c = t2 / 9;
    int ch  = c * CC + cq * 4;
    const float* src = wg + ((size_t)e * CIN + ch) * 9 + tap;
    unsigned u = 0;
    u = __builtin_amdgcn_cvt_pk_fp8_f32(src[0]  * 64.f, src[9]  * 64.f, u, 0);
    u = __builtin_amdgcn_cvt_pk_fp8_f32(src[18] * 64.f, src[27] * 64.f, u, 1);
    size_t base = (size_t)c * WCH;
    if (tap < 8) base += (tap >> 2) * WTG + e * 144 + (tap & 3) * 32 + cq * 4;
    else         base += W8OFF + e * 40 + cq * 4;
    *(unsigned*)(wimg + base) = u;
}

union Smem {
    struct { char xs[2][XBUF]; char wb[2][WCH]; } st;   // 31104 + 41984 = 73088 B
    float scores[256][65];                              // 66560 B (epilogue)
};

// (512,4): VGPR cap 128; R11/R12 A/B showed mild xr spill under this cap is
// FASTER than (512,2)'s no-spill (occupancy stays at the LDS-bound 2 blocks/CU).
__global__ __launch_bounds__(NTH, 4) void conv_mfma_kernel(
    const float* __restrict__ x, const char* __restrict__ wimg,
    const float* __restrict__ bias, float* __restrict__ out,
    int* __restrict__ gcount)
{
    __shared__ __align__(16) Smem sm;
    __shared__ int hist[NE];
    __shared__ float sbias[NE];

    const int tid  = threadIdx.x;        // 512 threads = 8 waves
    const int lane = tid & 63;
    const int wv   = tid >> 6;
    const int gm   = wv >> 1;            // m-group 0..3 (pixel rows gm*4..gm*4+3)
    const int h    = wv & 1;             // n-group 0..1 (32 experts each)

    // XCD affinity: image = blockIdx & 7 (round-robin dispatch -> image-per-XCD)
    const int id  = blockIdx.x;
    const int b   = id & 7;
    const int t   = id >> 3;             // 0..63 tile within image
    const int by0 = (t >> 3) * TS, bx0 = (t & 7) * TS;
    const float* xb = x + (size_t)b * CIN * HW;

    if (tid < NE) { hist[tid] = 0; sbias[tid] = bias[tid]; }

    const int er = lane & 15;
    const int kg = lane >> 4;

    // per-lane tap mapping for the two K=128 tapgroups: tap = tg*4 + kg
    const int tap0 = kg,      ky0 = tap0 / 3, kx0 = tap0 - 3 * ky0;
    const int tap1 = 4 + kg,  ky1 = tap1 / 3, kx1 = tap1 - 3 * ky1;
    const int abase0 = ky0 * HLX + er + kx0;     // add (gm*4+m)*HLX
    const int abase1 = ky1 * HLX + er + kx1;
    const int abase8 = 2 * HLX + er + 2;         // tap 8 = (ky2,kx2)

    // ---- hoisted staging addresses (loop-invariant) ----
    int srcIdx[3]; int ldsOff[3]; bool okm[3]; bool act[3];
    #pragma unroll
    for (int k = 0; k < 3; ++k) {
        int g  = tid + k * NTH;
        int s  = g % NSP, cp = g / NSP;
        int gy = by0 - 1 + s / HLX, gx = bx0 - 1 + s % HLX;
        act[k] = (g < NG);
        okm[k] = act[k] && ((unsigned)gy < (unsigned)HH) && ((unsigned)gx < (unsigned)WW);
        srcIdx[k] = okm[k] ? (cp * 8 * HW + gy * WW + gx) : 0;
        ldsOff[k] = s * XROW + cp * 8;           // canonical order, pad spreads banks
    }

    f32x4 acc[4][2];                     // [m 0..3][n 0..1]: 64 px x 32 e per wave
    #pragma unroll
    for (int m = 0; m < 4; ++m)
        #pragma unroll
        for (int n = 0; n < 2; ++n) acc[m][n] = (f32x4){0.f, 0.f, 0.f, 0.f};

    float xr[3][8];                      // in-flight x registers (T14 issue-early)

#define X_ISSUE(cc)                                                         \
    _Pragma("unroll")                                                       \
    for (int k = 0; k < 3; ++k) {                                           \
        if (act[k]) {                                                       \
            const float* p = xb + (size_t)(cc) * (CC * HW) + srcIdx[k];     \
            _Pragma("unroll")                                               \
            for (int q = 0; q < 8; ++q)                                     \
                xr[k][q] = okm[k] ? p[q * HW] : 0.f;                        \
        }                                                                   \
    }

#define X_WRITE(xd)                                                         \
    _Pragma("unroll")                                                       \
    for (int k = 0; k < 3; ++k) {                                           \
        if (act[k]) {                                                       \
            unsigned lo = 0, hi = 0;                                        \
            lo = __builtin_amdgcn_cvt_pk_fp8_f32(xr[k][0], xr[k][1], lo, 0); \
            lo = __builtin_amdgcn_cvt_pk_fp8_f32(xr[k][2], xr[k][3], lo, 1); \
            hi = __builtin_amdgcn_cvt_pk_fp8_f32(xr[k][4], xr[k][5], hi, 0); \
            hi = __builtin_amdgcn_cvt_pk_fp8_f32(xr[k][6], xr[k][7], hi, 1); \
            uint2 u2; u2.x = lo; u2.y = hi;                                 \
            *(uint2*)((xd) + ldsOff[k]) = u2;                               \
        }                                                                   \
    }

#define W_STAGE(cc, wd)                                                     \
    {                                                                       \
        const char* wsrc = wimg + (size_t)(cc) * WCH;                       \
        for (int i = tid; i < WCH / 16; i += NTH)                           \
            GLDS16(wsrc + i * 16, (wd) + i * 16);                           \
    }

    // K=128 tapgroup phase: lane-group kg <-> tap tg*4+kg; 32B/lane from one row
#define TG_PHASE(ABASE, WOFF, xcur, wcur)                                   \
    {                                                                       \
        i32x8 Bf[2];                                                        \
        _Pragma("unroll")                                                   \
        for (int n = 0; n < 2; ++n) {                                       \
            const char* wp = (wcur) + (WOFF) + (h * 32 + n * 16 + er) * 144 + kg * 32; \
            Bf[n] = LDB256(wp);                                             \
        }                                                                   \
        _Pragma("unroll")                                                   \
        for (int m = 0; m < 4; ++m) {                                       \
            const char* xp = (xcur) + ((gm * 4 + m) * HLX + (ABASE)) * XROW; \
            i32x8 Af = LDB256(xp);                                          \
            _Pragma("unroll")                                               \
            for (int n = 0; n < 2; ++n)                                     \
                acc[m][n] = __builtin_amdgcn_mfma_scale_f32_16x16x128_f8f6f4( \
                    Af, Bf[n], acc[m][n], 0, 0, 0, 127, 0, 127);            \
        }                                                                   \
    }

    // K=32 tail for tap 8
#define TAP8_PHASE(xcur, wcur)                                              \
    {                                                                       \
        long Bf8[2];                                                        \
        _Pragma("unroll")                                                   \
        for (int n = 0; n < 2; ++n)                                         \
            Bf8[n] = *(const long*)((wcur) + W8OFF + (h * 32 + n * 16 + er) * 40 + kg * 8); \
        _Pragma("unroll")                                                   \
        for (int m = 0; m < 4; ++m) {                                       \
            long Af8 = *(const long*)((xcur) + ((gm * 4 + m) * HLX + abase8) * XROW + kg * 8); \
            _Pragma("unroll")                                               \
            for (int n = 0; n < 2; ++n)                                     \
                acc[m][n] = __builtin_amdgcn_mfma_f32_16x16x32_fp8_fp8(Af8, Bf8[n], acc[m][n], 0, 0, 0); \
        }                                                                   \
    }

    // ---- prologue: stage chunk 0 ----
    X_ISSUE(0)
    W_STAGE(0, sm.st.wb[0])
    X_WRITE(sm.st.xs[0])
    __syncthreads();

    #pragma unroll 1
    for (int c = 0; c < NCH; ++c) {
        char* xcur = sm.st.xs[c & 1];
        char* xalt = sm.st.xs[(c + 1) & 1];
        char* wcur = sm.st.wb[c & 1];
        char* walt = sm.st.wb[(c + 1) & 1];
        const bool more = (c < NCH - 1);

        if (more) {
            X_ISSUE(c + 1)               // x loads in flight under compute
            W_STAGE(c + 1, walt)         // async glds into other w buffer
        }
        __builtin_amdgcn_sched_barrier(0);
        TG_PHASE(abase0, 0,   xcur, wcur)
        TG_PHASE(abase1, WTG, xcur, wcur)
        if (more) { X_WRITE(xalt) }      // other buffer: no wait needed
        TAP8_PHASE(xcur, wcur)
        __syncthreads();                 // single barrier: drains glds + ds_writes
    }

    // ---- epilogue: sigmoid(logit)+bias -> LDS scores [pixel][expert]; w was x64 ----
    #pragma unroll
    for (int m = 0; m < 4; ++m) {
        int pixbase = (gm * 4 + m) * 16 + kg * 4;   // C: row=(lane>>4)*4+reg, col=lane&15
        #pragma unroll
        for (int n = 0; n < 2; ++n) {
            int e = h * 32 + n * 16 + er;
            float bval = sbias[e];
            #pragma unroll
            for (int r = 0; r < 4; ++r)
                sm.scores[pixbase + r][e] =
                    __builtin_amdgcn_rcpf(1.f + __expf(-acc[m][n][r] * 0.015625f)) + bval;
        }
    }
    __syncthreads();

    // ---- per-pixel top-8: packed keys (score bits | 63-e), u32 max-tree ----
    if (tid < 256) {
        unsigned key[64];
        #pragma unroll
        for (int e = 0; e < 64; ++e)   // scores > 0 -> bit order = float order
            key[e] = (__float_as_uint(sm.scores[tid][e]) & ~63u) | (unsigned)(63 - e);

        float selv[TOPK]; int seli[TOPK];
        #pragma unroll
        for (int j = 0; j < TOPK; ++j) {
            unsigned t32[32];
            #pragma unroll
            for (int e = 0; e < 32; ++e) t32[e] = key[2*e] > key[2*e+1] ? key[2*e] : key[2*e+1];
            #pragma unroll
            for (int e = 0; e < 16; ++e) t32[e] = t32[2*e] > t32[2*e+1] ? t32[2*e] : t32[2*e+1];
            #pragma unroll
            for (int e = 0; e < 8; ++e)  t32[e] = t32[2*e] > t32[2*e+1] ? t32[2*e] : t32[2*e+1];
            #pragma unroll
            for (int e = 0; e < 4; ++e)  t32[e] = t32[2*e] > t32[2*e+1] ? t32[2*e] : t32[2*e+1];
            unsigned best = t32[0] > t32[1] ? t32[0] : t32[1];
            unsigned b2   = t32[2] > t32[3] ? t32[2] : t32[3];
            best = best > b2 ? best : b2;

            int e = 63 - (int)(best & 63u);
            seli[j] = e;
            selv[j] = __uint_as_float(best & ~63u) - sbias[e];
            #pragma unroll
            for (int e2 = 0; e2 < 64; ++e2) key[e2] = (key[e2] == best) ? 0u : key[e2];
        }
        float mx = selv[0];
        #pragma unroll
        for (int j = 1; j < TOPK; ++j) mx = fmaxf(mx, selv[j]);
        float ex[TOPK]; float ssum = 0.f;
        #pragma unroll
        for (int j = 0; j < TOPK; ++j) { ex[j] = __expf(selv[j] - mx); ssum += ex[j]; }
        const float inv = 1.f / ssum;

        const int pyg = by0 + (tid >> 4), pxg = bx0 + (tid & 15);
        #pragma unroll
        for (int j = 0; j < TOPK; ++j) {
            size_t o = ((size_t)(b * TOPK + j) * HH + pyg) * WW + pxg;
            out[W_OFF + o] = ex[j] * inv;
            out[I_OFF + o] = (float)seli[j];
            atomicAdd(&hist[seli[j]], 1);
        }
    }
    __syncthreads();
    if (tid < NE) atomicAdd(&gcount[tid], hist[tid]);
}

__global__ void finalize_kernel(const float* __restrict__ bias,
                                const float* __restrict__ history,
                                const int* __restrict__ gcount,
                                float* __restrict__ out)
{
    const int e = threadIdx.x;   // 64 threads = 1 wave
    float c = history[e] + (float)gcount[e];
    if (__all(c > 1e8f)) c = fmodf(c, 1e8f);
    float sum = c;
    #pragma unroll
    for (int off = 32; off > 0; off >>= 1) sum += __shfl_down(sum, off);
    float mean = __shfl(sum, 0) * (1.f / 64.f);
    float d = mean - c;
    float sg = (d > 0.f) ? 1.f : ((d < 0.f) ? -1.f : 0.f);
    out[C_OFF + e]  = c;
    out[NB_OFF + e] = bias[e] + 0.001f * sg;
}

extern "C" void kernel_launch(void* const* d_in, const int* in_sizes, int n_in,
                              void* d_out, int out_size, void* d_ws, size_t ws_size,
                              hipStream_t stream) {
    const float* x       = (const float*)d_in[0];
    const float* wg      = (const float*)d_in[1];
    const float* bias    = (const float*)d_in[2];
    const float* history = (const float*)d_in[3];
    float* out = (float*)d_out;

    char* wimg  = (char*)d_ws;
    int* gcount = (int*)((char*)d_ws + WIMG_BYTES);

    prep_w<<<(NCH * 9 * NE * 8 + 255) / 256, 256, 0, stream>>>(wg, wimg, gcount);
    conv_mfma_kernel<<<512, NTH, 0, stream>>>(x, wimg, bias, out, gcount);
    finalize_kernel<<<1, 64, 0, stream>>>(bias, history, gcount, out);
}

// Round 16
// 58.192 us; speedup vs baseline: 2.8181x; 2.8181x over previous
//
#include <hip/hip_runtime.h>

// Problem constants
#define BB 8
#define CIN 256
#define NE 64
#define HH 128
#define WW 128
#define HW (HH*WW)
#define TOPK 8

#define TS   16              // 16x16 pixel tile, 512 blocks of 512 threads
#define NTH  512
#define HLX  18
#define NSP  (HLX*HLX)       // 324 spatial positions incl halo
#define NG   (NSP*4)         // 1296 (s, cp) staging groups, 8 ch each
#define CC   32              // channels per K-chunk
#define NCH  (CIN/CC)        // 8 chunks
#define XROW 32              // x LDS row bytes: 32 ch fp8
#define XBUF (NSP*XROW)      // 10368 B per x buffer
#define WCH  (9*NE*XROW)     // 18432 B per w chunk

#define XSWZ(v) (((v) & 15) << 3)   // XOR-swizzle byte bits 3..6 (8B granule preserved)

// d_out layout (float32 view): weights | indices | counts | new_bias
#define W_OFF  0
#define I_OFF  (BB*TOPK*HH*WW)
#define C_OFF  (2*BB*TOPK*HH*WW)
#define NB_OFF (C_OFF + NE)

#define WIMG_BYTES (NCH*WCH)   // 147456

using f32x4 = __attribute__((ext_vector_type(4))) float;

#define GLDS16(gsrc, ldst) __builtin_amdgcn_global_load_lds( \
    (const __attribute__((address_space(1))) void*)(gsrc),   \
    (__attribute__((address_space(3))) void*)(ldst), 16, 0, 0)

// ---- prep: w fp32 [e][cin][3][3] -> fp8 e4m3 (x64 scaled) pre-swizzled image ----
// Also zeroes gcount (replaces the memset dispatch; kernel boundary = coherence point).
__global__ void prep_w(const float* __restrict__ wg, char* __restrict__ wimg,
                       int* __restrict__ gcount) {
    if (blockIdx.x == 0 && threadIdx.x < NE) gcount[threadIdx.x] = 0;
    int i = blockIdx.x * 256 + threadIdx.x;
    if (i >= NCH * 9 * NE * 8) return;
    int cp = i & 7; int t = i >> 3;
    int e  = t & 63; int t2 = t >> 6;
    int tap = t2 % 9; int c = t2 / 9;
    int ch  = c * CC + cp * 4;
    const float* src = wg + ((size_t)e * CIN + ch) * 9 + tap;
    unsigned u = 0;
    u = __builtin_amdgcn_cvt_pk_fp8_f32(src[0]  * 64.f, src[9]  * 64.f, u, 0);
    u = __builtin_amdgcn_cvt_pk_fp8_f32(src[18] * 64.f, src[27] * 64.f, u, 1);
    int row = tap * 64 + e;
    *(unsigned*)(wimg + (size_t)c * WCH + ((row * 32 + cp * 4) ^ XSWZ(row))) = u;
}

union Smem {
    struct { char xs[2][XBUF]; char wb[2][WCH]; } st;   // 57600 B
    float scores[256][65];                              // 66560 B (epilogue)
};

// (512,4): VGPR cap 128. R12: raising the cap (512,2) kills occupancy. R16: cut
// the xr live-range instead (2-phase issue, max 16 live) to kill the spill.
__global__ __launch_bounds__(NTH, 4) void conv_mfma_kernel(
    const float* __restrict__ x, const char* __restrict__ wimg,
    const float* __restrict__ bias, float* __restrict__ out,
    int* __restrict__ gcount)
{
    __shared__ __align__(16) Smem sm;
    __shared__ int hist[NE];
    __shared__ float sbias[NE];

    const int tid  = threadIdx.x;        // 512 threads = 8 waves
    const int lane = tid & 63;
    const int wv   = tid >> 6;
    const int gm   = wv >> 1;            // m-group 0..3 (pixel rows gm*4..gm*4+3)
    const int h    = wv & 1;             // n-group 0..1 (32 experts each)

    // XCD affinity: image = blockIdx & 7 (round-robin dispatch -> image-per-XCD)
    const int id  = blockIdx.x;
    const int b   = id & 7;
    const int t   = id >> 3;             // 0..63 tile within image
    const int by0 = (t >> 3) * TS, bx0 = (t & 7) * TS;
    const float* xb = x + (size_t)b * CIN * HW;

    if (tid < NE) { hist[tid] = 0; sbias[tid] = bias[tid]; }

    const int er = lane & 15;
    const int kg = lane >> 4;

    // ---- hoisted staging addresses (loop-invariant) ----
    int srcIdx[3]; int ldsOff[3]; bool okm[3]; bool act[3];
    #pragma unroll
    for (int k = 0; k < 3; ++k) {
        int g  = tid + k * NTH;
        int s  = g % NSP, cp = g / NSP;
        int gy = by0 - 1 + s / HLX, gx = bx0 - 1 + s % HLX;
        act[k] = (g < NG);
        okm[k] = act[k] && ((unsigned)gy < (unsigned)HH) && ((unsigned)gx < (unsigned)WW);
        srcIdx[k] = okm[k] ? (cp * 8 * HW + gy * WW + gx) : 0;
        ldsOff[k] = (s * 32 + cp * 8) ^ XSWZ(s);
    }

    f32x4 acc[4][2];                     // [m 0..3][n 0..1]: 64 px x 32 e per wave
    #pragma unroll
    for (int m = 0; m < 4; ++m)
        #pragma unroll
        for (int n = 0; n < 2; ++n) acc[m][n] = (f32x4){0.f, 0.f, 0.f, 0.f};

    float xr1[2][8], xr2[1][8];          // two in-flight groups: 16 + 8 regs

#define X_ISSUE_G(cc, K0, KN, XR)                                           \
    _Pragma("unroll")                                                       \
    for (int k = 0; k < (KN); ++k) {                                        \
        if (act[K0 + k]) {                                                  \
            const float* p = xb + (size_t)(cc) * (CC * HW) + srcIdx[K0 + k];\
            _Pragma("unroll")                                               \
            for (int q = 0; q < 8; ++q)                                     \
                XR[k][q] = okm[K0 + k] ? p[q * HW] : 0.f;                   \
        }                                                                   \
    }

    // convert 8 floats -> 8 fp8 (e4m3), swizzled b64 write
#define X_WRITE_G(xd, K0, KN, XR)                                           \
    _Pragma("unroll")                                                       \
    for (int k = 0; k < (KN); ++k) {                                        \
        if (act[K0 + k]) {                                                  \
            unsigned lo = 0, hi = 0;                                        \
            lo = __builtin_amdgcn_cvt_pk_fp8_f32(XR[k][0], XR[k][1], lo, 0); \
            lo = __builtin_amdgcn_cvt_pk_fp8_f32(XR[k][2], XR[k][3], lo, 1); \
            hi = __builtin_amdgcn_cvt_pk_fp8_f32(XR[k][4], XR[k][5], hi, 0); \
            hi = __builtin_amdgcn_cvt_pk_fp8_f32(XR[k][6], XR[k][7], hi, 1); \
            uint2 u2; u2.x = lo; u2.y = hi;                                 \
            *(uint2*)((xd) + ldsOff[K0 + k]) = u2;                          \
        }                                                                   \
    }

#define W_STAGE(cc, wd)                                                     \
    {                                                                       \
        const char* wsrc = wimg + (size_t)(cc) * WCH;                       \
        for (int i = tid; i < WCH / 16; i += NTH)                           \
            GLDS16(wsrc + i * 16, (wd) + i * 16);                           \
    }

#define KX_PHASE(KX, xcur, wcur)                                            \
    {                                                                       \
        long A[6];                                                          \
        _Pragma("unroll")                                                   \
        for (int rr = 0; rr < 6; ++rr) {                                    \
            int s = (gm * 4 + rr) * HLX + er + (KX);                        \
            A[rr] = *(const long*)((xcur) + ((s * 32 + kg * 8) ^ XSWZ(s))); \
        }                                                                   \
        _Pragma("unroll")                                                   \
        for (int ky = 0; ky < 3; ++ky) {                                    \
            const int tap = ky * 3 + (KX);                                  \
            long Bf[2];                                                     \
            _Pragma("unroll")                                               \
            for (int n = 0; n < 2; ++n) {                                   \
                int row = tap * 64 + h * 32 + n * 16 + er;                  \
                Bf[n] = *(const long*)((wcur) + ((row * 32 + kg * 8) ^ XSWZ(row))); \
            }                                                               \
            _Pragma("unroll")                                               \
            for (int n = 0; n < 2; ++n)                                     \
                _Pragma("unroll")                                           \
                for (int m = 0; m < 4; ++m)                                 \
                    acc[m][n] = __builtin_amdgcn_mfma_f32_16x16x32_fp8_fp8(A[m + ky], Bf[n], acc[m][n], 0, 0, 0); \
        }                                                                   \
    }

    // ---- prologue: stage chunk 0 ----
    X_ISSUE_G(0, 0, 2, xr1)
    X_ISSUE_G(0, 2, 1, xr2)
    W_STAGE(0, sm.st.wb[0])
    X_WRITE_G(sm.st.xs[0], 0, 2, xr1)
    X_WRITE_G(sm.st.xs[0], 2, 1, xr2)
    __syncthreads();

    #pragma unroll 1
    for (int c = 0; c < NCH; ++c) {
        char* xcur = sm.st.xs[c & 1];
        char* xalt = sm.st.xs[(c + 1) & 1];
        char* wcur = sm.st.wb[c & 1];
        char* walt = sm.st.wb[(c + 1) & 1];
        const bool more = (c < NCH - 1);

        if (more) {
            X_ISSUE_G(c + 1, 0, 2, xr1)  // 16 regs in flight
            W_STAGE(c + 1, walt)         // async glds into other w buffer
        }
        __builtin_amdgcn_sched_barrier(0);
        KX_PHASE(0, xcur, wcur)
        if (more) {
            X_WRITE_G(xalt, 0, 2, xr1)   // retire group 1 (other buffer, no wait)
            X_ISSUE_G(c + 1, 2, 1, xr2)  // 8 regs in flight
        }
        __builtin_amdgcn_sched_barrier(0);
        KX_PHASE(1, xcur, wcur)
        if (more) { X_WRITE_G(xalt, 2, 1, xr2) }
        KX_PHASE(2, xcur, wcur)
        __syncthreads();                 // single barrier: drains glds + ds_writes
    }

    // ---- epilogue: sigmoid(logit)+bias -> LDS scores [pixel][expert]; w was x64 ----
    #pragma unroll
    for (int m = 0; m < 4; ++m) {
        int pixbase = (gm * 4 + m) * 16 + kg * 4;   // C: row=(lane>>4)*4+reg, col=lane&15
        #pragma unroll
        for (int n = 0; n < 2; ++n) {
            int e = h * 32 + n * 16 + er;
            float bval = sbias[e];
            #pragma unroll
            for (int r = 0; r < 4; ++r)
                sm.scores[pixbase + r][e] =
                    __builtin_amdgcn_rcpf(1.f + __expf(-acc[m][n][r] * 0.015625f)) + bval;
        }
    }
    __syncthreads();

    // ---- per-pixel top-8: packed keys (score bits | 63-e), u32 max-tree ----
    if (tid < 256) {
        unsigned key[64];
        #pragma unroll
        for (int e = 0; e < 64; ++e)   // scores > 0 -> bit order = float order
            key[e] = (__float_as_uint(sm.scores[tid][e]) & ~63u) | (unsigned)(63 - e);

        float selv[TOPK]; int seli[TOPK];
        #pragma unroll
        for (int j = 0; j < TOPK; ++j) {
            unsigned t32[32];
            #pragma unroll
            for (int e = 0; e < 32; ++e) t32[e] = key[2*e] > key[2*e+1] ? key[2*e] : key[2*e+1];
            #pragma unroll
            for (int e = 0; e < 16; ++e) t32[e] = t32[2*e] > t32[2*e+1] ? t32[2*e] : t32[2*e+1];
            #pragma unroll
            for (int e = 0; e < 8; ++e)  t32[e] = t32[2*e] > t32[2*e+1] ? t32[2*e] : t32[2*e+1];
            #pragma unroll
            for (int e = 0; e < 4; ++e)  t32[e] = t32[2*e] > t32[2*e+1] ? t32[2*e] : t32[2*e+1];
            unsigned best = t32[0] > t32[1] ? t32[0] : t32[1];
            unsigned b2   = t32[2] > t32[3] ? t32[2] : t32[3];
            best = best > b2 ? best : b2;

            int e = 63 - (int)(best & 63u);
            seli[j] = e;
            selv[j] = __uint_as_float(best & ~63u) - sbias[e];
            #pragma unroll
            for (int e2 = 0; e2 < 64; ++e2) key[e2] = (key[e2] == best) ? 0u : key[e2];
        }
        float mx = selv[0];
        #pragma unroll
        for (int j = 1; j < TOPK; ++j) mx = fmaxf(mx, selv[j]);
        float ex[TOPK]; float ssum = 0.f;
        #pragma unroll
        for (int j = 0; j < TOPK; ++j) { ex[j] = __expf(selv[j] - mx); ssum += ex[j]; }
        const float inv = 1.f / ssum;

        const int pyg = by0 + (tid >> 4), pxg = bx0 + (tid & 15);
        #pragma unroll
        for (int j = 0; j < TOPK; ++j) {
            size_t o = ((size_t)(b * TOPK + j) * HH + pyg) * WW + pxg;
            out[W_OFF + o] = ex[j] * inv;
            out[I_OFF + o] = (float)seli[j];
            atomicAdd(&hist[seli[j]], 1);
        }
    }
    __syncthreads();
    if (tid < NE) atomicAdd(&gcount[tid], hist[tid]);
}

__global__ void finalize_kernel(const float* __restrict__ bias,
                                const float* __restrict__ history,
                                const int* __restrict__ gcount,
                                float* __restrict__ out)
{
    const int e = threadIdx.x;   // 64 threads = 1 wave
    float c = history[e] + (float)gcount[e];
    if (__all(c > 1e8f)) c = fmodf(c, 1e8f);
    float sum = c;
    #pragma unroll
    for (int off = 32; off > 0; off >>= 1) sum += __shfl_down(sum, off);
    float mean = __shfl(sum, 0) * (1.f / 64.f);
    float d = mean - c;
    float sg = (d > 0.f) ? 1.f : ((d < 0.f) ? -1.f : 0.f);
    out[C_OFF + e]  = c;
    out[NB_OFF + e] = bias[e] + 0.001f * sg;
}

extern "C" void kernel_launch(void* const* d_in, const int* in_sizes, int n_in,
                              void* d_out, int out_size, void* d_ws, size_t ws_size,
                              hipStream_t stream) {
    const float* x       = (const float*)d_in[0];
    const float* wg      = (const float*)d_in[1];
    const float* bias    = (const float*)d_in[2];
    const float* history = (const float*)d_in[3];
    float* out = (float*)d_out;

    char* wimg  = (char*)d_ws;
    int* gcount = (int*)((char*)d_ws + WIMG_BYTES);

    prep_w<<<(NCH * 9 * NE * 8 + 255) / 256, 256, 0, stream>>>(wg, wimg, gcount);
    conv_mfma_kernel<<<512, NTH, 0, stream>>>(x, wimg, bias, out, gcount);
    finalize_kernel<<<1, 64, 0, stream>>>(bias, history, gcount, out);
}

// Round 17
// 55.065 us; speedup vs baseline: 2.9781x; 1.0568x over previous
//
#include <hip/hip_runtime.h>

// Problem constants
#define BB 8
#define CIN 256
#define NE 64
#define HH 128
#define WW 128
#define HW (HH*WW)
#define TOPK 8

#define TS   16              // 16x16 pixel tile, 512 blocks of 512 threads
#define NTH  512
#define HLX  18
#define NSP  (HLX*HLX)       // 324 spatial positions incl halo
#define NG   (NSP*4)         // 1296 (s, cp) staging groups, 8 ch each
#define CC   32              // channels per K-chunk
#define NCH  (CIN/CC)        // 8 chunks
#define XROW 32              // x LDS row bytes: 32 ch fp8
#define XBUF (NSP*XROW)      // 10368 B per x buffer
#define WCH  (9*NE*XROW)     // 18432 B per w chunk

#define XSWZ(v) (((v) & 15) << 3)   // XOR-swizzle byte bits 3..6 (8B granule preserved)

// d_out layout (float32 view): weights | indices | counts | new_bias
#define W_OFF  0
#define I_OFF  (BB*TOPK*HH*WW)
#define C_OFF  (2*BB*TOPK*HH*WW)
#define NB_OFF (C_OFF + NE)

#define WIMG_BYTES (NCH*WCH)   // 147456

using f32x4 = __attribute__((ext_vector_type(4))) float;

#define GLDS16(gsrc, ldst) __builtin_amdgcn_global_load_lds( \
    (const __attribute__((address_space(1))) void*)(gsrc),   \
    (__attribute__((address_space(3))) void*)(ldst), 16, 0, 0)

// ---- prep: w fp32 [e][cin][3][3] -> fp8 e4m3 (x64 scaled) pre-swizzled image ----
// Also zeroes gcount (replaces the memset dispatch; no fence needed -- the
// kernel boundary before conv_mfma_kernel is the coherence point).
__global__ void prep_w(const float* __restrict__ wg, char* __restrict__ wimg,
                       int* __restrict__ gcount) {
    if (blockIdx.x == 0 && threadIdx.x < NE) gcount[threadIdx.x] = 0;
    int i = blockIdx.x * 256 + threadIdx.x;
    if (i >= NCH * 9 * NE * 8) return;
    int cp = i & 7; int t = i >> 3;
    int e  = t & 63; int t2 = t >> 6;
    int tap = t2 % 9; int c = t2 / 9;
    int ch  = c * CC + cp * 4;
    const float* src = wg + ((size_t)e * CIN + ch) * 9 + tap;
    unsigned u = 0;
    u = __builtin_amdgcn_cvt_pk_fp8_f32(src[0]  * 64.f, src[9]  * 64.f, u, 0);
    u = __builtin_amdgcn_cvt_pk_fp8_f32(src[18] * 64.f, src[27] * 64.f, u, 1);
    int row = tap * 64 + e;
    *(unsigned*)(wimg + (size_t)c * WCH + ((row * 32 + cp * 4) ^ XSWZ(row))) = u;
}

union Smem {
    struct { char xs[2][XBUF]; char wb[2][WCH]; } st;   // 57600 B
    float scores[256][65];                              // 66560 B (epilogue)
};

// (512,4): VGPR cap 128; R11/R12/R16 A/B showed the compiler's mild xr spill
// under this cap beats both the no-spill (512,2) config and live-range splits.
__global__ __launch_bounds__(NTH, 4) void conv_mfma_kernel(
    const float* __restrict__ x, const char* __restrict__ wimg,
    const float* __restrict__ bias, float* __restrict__ out,
    int* __restrict__ gcount)
{
    __shared__ __align__(16) Smem sm;
    __shared__ int hist[NE];
    __shared__ float sbias[NE];

    const int tid  = threadIdx.x;        // 512 threads = 8 waves
    const int lane = tid & 63;
    const int wv   = tid >> 6;
    const int gm   = wv >> 1;            // m-group 0..3 (pixel rows gm*4..gm*4+3)
    const int h    = wv & 1;             // n-group 0..1 (32 experts each)

    // XCD affinity: image = blockIdx & 7 (round-robin dispatch -> image-per-XCD)
    const int id  = blockIdx.x;
    const int b   = id & 7;
    const int t   = id >> 3;             // 0..63 tile within image
    const int by0 = (t >> 3) * TS, bx0 = (t & 7) * TS;
    const float* xb = x + (size_t)b * CIN * HW;

    if (tid < NE) { hist[tid] = 0; sbias[tid] = bias[tid]; }

    const int er = lane & 15;
    const int kg = lane >> 4;

    // ---- hoisted staging addresses (loop-invariant) ----
    int srcIdx[3]; int ldsOff[3]; bool okm[3]; bool act[3];
    #pragma unroll
    for (int k = 0; k < 3; ++k) {
        int g  = tid + k * NTH;
        int s  = g % NSP, cp = g / NSP;
        int gy = by0 - 1 + s / HLX, gx = bx0 - 1 + s % HLX;
        act[k] = (g < NG);
        okm[k] = act[k] && ((unsigned)gy < (unsigned)HH) && ((unsigned)gx < (unsigned)WW);
        srcIdx[k] = okm[k] ? (cp * 8 * HW + gy * WW + gx) : 0;
        ldsOff[k] = (s * 32 + cp * 8) ^ XSWZ(s);
    }

    f32x4 acc[4][2];                     // [m 0..3][n 0..1]: 64 px x 32 e per wave
    #pragma unroll
    for (int m = 0; m < 4; ++m)
        #pragma unroll
        for (int n = 0; n < 2; ++n) acc[m][n] = (f32x4){0.f, 0.f, 0.f, 0.f};

    float xr[3][8];                      // in-flight x registers (T14 issue-early)

#define X_ISSUE(cc)                                                         \
    _Pragma("unroll")                                                       \
    for (int k = 0; k < 3; ++k) {                                           \
        if (act[k]) {                                                       \
            const float* p = xb + (size_t)(cc) * (CC * HW) + srcIdx[k];     \
            _Pragma("unroll")                                               \
            for (int q = 0; q < 8; ++q)                                     \
                xr[k][q] = okm[k] ? p[q * HW] : 0.f;                        \
        }                                                                   \
    }

    // convert 8 floats -> 8 fp8 (e4m3), swizzled b64 write
#define X_WRITE(xd)                                                         \
    _Pragma("unroll")                                                       \
    for (int k = 0; k < 3; ++k) {                                           \
        if (act[k]) {                                                       \
            unsigned lo = 0, hi = 0;                                        \
            lo = __builtin_amdgcn_cvt_pk_fp8_f32(xr[k][0], xr[k][1], lo, 0); \
            lo = __builtin_amdgcn_cvt_pk_fp8_f32(xr[k][2], xr[k][3], lo, 1); \
            hi = __builtin_amdgcn_cvt_pk_fp8_f32(xr[k][4], xr[k][5], hi, 0); \
            hi = __builtin_amdgcn_cvt_pk_fp8_f32(xr[k][6], xr[k][7], hi, 1); \
            uint2 u2; u2.x = lo; u2.y = hi;                                 \
            *(uint2*)((xd) + ldsOff[k]) = u2;                               \
        }                                                                   \
    }

#define W_STAGE(cc, wd)                                                     \
    {                                                                       \
        const char* wsrc = wimg + (size_t)(cc) * WCH;                       \
        for (int i = tid; i < WCH / 16; i += NTH)                           \
            GLDS16(wsrc + i * 16, (wd) + i * 16);                           \
    }

#define KX_PHASE(KX, xcur, wcur)                                            \
    {                                                                       \
        long A[6];                                                          \
        _Pragma("unroll")                                                   \
        for (int rr = 0; rr < 6; ++rr) {                                    \
            int s = (gm * 4 + rr) * HLX + er + (KX);                        \
            A[rr] = *(const long*)((xcur) + ((s * 32 + kg * 8) ^ XSWZ(s))); \
        }                                                                   \
        _Pragma("unroll")                                                   \
        for (int ky = 0; ky < 3; ++ky) {                                    \
            const int tap = ky * 3 + (KX);                                  \
            long Bf[2];                                                     \
            _Pragma("unroll")                                               \
            for (int n = 0; n < 2; ++n) {                                   \
                int row = tap * 64 + h * 32 + n * 16 + er;                  \
                Bf[n] = *(const long*)((wcur) + ((row * 32 + kg * 8) ^ XSWZ(row))); \
            }                                                               \
            _Pragma("unroll")                                               \
            for (int n = 0; n < 2; ++n)                                     \
                _Pragma("unroll")                                           \
                for (int m = 0; m < 4; ++m)                                 \
                    acc[m][n] = __builtin_amdgcn_mfma_f32_16x16x32_fp8_fp8(A[m + ky], Bf[n], acc[m][n], 0, 0, 0); \
        }                                                                   \
    }

    // ---- prologue: stage chunk 0 ----
    X_ISSUE(0)
    W_STAGE(0, sm.st.wb[0])
    X_WRITE(sm.st.xs[0])
    __syncthreads();

    #pragma unroll 1
    for (int c = 0; c < NCH; ++c) {
        char* xcur = sm.st.xs[c & 1];
        char* xalt = sm.st.xs[(c + 1) & 1];
        char* wcur = sm.st.wb[c & 1];
        char* walt = sm.st.wb[(c + 1) & 1];
        const bool more = (c < NCH - 1);

        if (more) {
            X_ISSUE(c + 1)               // x loads in flight under compute
            W_STAGE(c + 1, walt)         // async glds into other w buffer
        }
        __builtin_amdgcn_sched_barrier(0);
        KX_PHASE(0, xcur, wcur)
        KX_PHASE(1, xcur, wcur)
        if (more) { X_WRITE(xalt) }      // other buffer: no wait needed
        KX_PHASE(2, xcur, wcur)
        __syncthreads();                 // single barrier: drains glds + ds_writes
    }

    // ---- epilogue: sigmoid(logit)+bias -> LDS scores [pixel][expert]; w was x64 ----
    #pragma unroll
    for (int m = 0; m < 4; ++m) {
        int pixbase = (gm * 4 + m) * 16 + kg * 4;   // C: row=(lane>>4)*4+reg, col=lane&15
        #pragma unroll
        for (int n = 0; n < 2; ++n) {
            int e = h * 32 + n * 16 + er;
            float bval = sbias[e];
            #pragma unroll
            for (int r = 0; r < 4; ++r)
                sm.scores[pixbase + r][e] =
                    __builtin_amdgcn_rcpf(1.f + __expf(-acc[m][n][r] * 0.015625f)) + bval;
        }
    }
    __syncthreads();

    // ---- per-pixel top-8: packed keys (score bits | 63-e), u32 max-tree ----
    if (tid < 256) {
        unsigned key[64];
        #pragma unroll
        for (int e = 0; e < 64; ++e)   // scores > 0 -> bit order = float order
            key[e] = (__float_as_uint(sm.scores[tid][e]) & ~63u) | (unsigned)(63 - e);

        float selv[TOPK]; int seli[TOPK];
        #pragma unroll
        for (int j = 0; j < TOPK; ++j) {
            unsigned t32[32];
            #pragma unroll
            for (int e = 0; e < 32; ++e) t32[e] = key[2*e] > key[2*e+1] ? key[2*e] : key[2*e+1];
            #pragma unroll
            for (int e = 0; e < 16; ++e) t32[e] = t32[2*e] > t32[2*e+1] ? t32[2*e] : t32[2*e+1];
            #pragma unroll
            for (int e = 0; e < 8; ++e)  t32[e] = t32[2*e] > t32[2*e+1] ? t32[2*e] : t32[2*e+1];
            #pragma unroll
            for (int e = 0; e < 4; ++e)  t32[e] = t32[2*e] > t32[2*e+1] ? t32[2*e] : t32[2*e+1];
            unsigned best = t32[0] > t32[1] ? t32[0] : t32[1];
            unsigned b2   = t32[2] > t32[3] ? t32[2] : t32[3];
            best = best > b2 ? best : b2;

            int e = 63 - (int)(best & 63u);
            seli[j] = e;
            selv[j] = __uint_as_float(best & ~63u) - sbias[e];
            #pragma unroll
            for (int e2 = 0; e2 < 64; ++e2) key[e2] = (key[e2] == best) ? 0u : key[e2];
        }
        float mx = selv[0];
        #pragma unroll
        for (int j = 1; j < TOPK; ++j) mx = fmaxf(mx, selv[j]);
        float ex[TOPK]; float ssum = 0.f;
        #pragma unroll
        for (int j = 0; j < TOPK; ++j) { ex[j] = __expf(selv[j] - mx); ssum += ex[j]; }
        const float inv = 1.f / ssum;

        const int pyg = by0 + (tid >> 4), pxg = bx0 + (tid & 15);
        #pragma unroll
        for (int j = 0; j < TOPK; ++j) {
            size_t o = ((size_t)(b * TOPK + j) * HH + pyg) * WW + pxg;
            out[W_OFF + o] = ex[j] * inv;
            out[I_OFF + o] = (float)seli[j];
            atomicAdd(&hist[seli[j]], 1);
        }
    }
    __syncthreads();
    if (tid < NE) atomicAdd(&gcount[tid], hist[tid]);
}

__global__ void finalize_kernel(const float* __restrict__ bias,
                                const float* __restrict__ history,
                                const int* __restrict__ gcount,
                                float* __restrict__ out)
{
    const int e = threadIdx.x;   // 64 threads = 1 wave
    float c = history[e] + (float)gcount[e];
    if (__all(c > 1e8f)) c = fmodf(c, 1e8f);
    float sum = c;
    #pragma unroll
    for (int off = 32; off > 0; off >>= 1) sum += __shfl_down(sum, off);
    float mean = __shfl(sum, 0) * (1.f / 64.f);
    float d = mean - c;
    float sg = (d > 0.f) ? 1.f : ((d < 0.f) ? -1.f : 0.f);
    out[C_OFF + e]  = c;
    out[NB_OFF + e] = bias[e] + 0.001f * sg;
}

extern "C" void kernel_launch(void* const* d_in, const int* in_sizes, int n_in,
                              void* d_out, int out_size, void* d_ws, size_t ws_size,
                              hipStream_t stream) {
    const float* x       = (const float*)d_in[0];
    const float* wg      = (const float*)d_in[1];
    const float* bias    = (const float*)d_in[2];
    const float* history = (const float*)d_in[3];
    float* out = (float*)d_out;

    char* wimg  = (char*)d_ws;
    int* gcount = (int*)((char*)d_ws + WIMG_BYTES);

    prep_w<<<(NCH * 9 * NE * 8 + 255) / 256, 256, 0, stream>>>(wg, wimg, gcount);
    conv_mfma_kernel<<<512, NTH, 0, stream>>>(x, wimg, bias, out, gcount);
    finalize_kernel<<<1, 64, 0, stream>>>(bias, history, gcount, out);
}